// Round 6
// baseline (541.927 us; speedup 1.0000x reference)
//
#include <hip/hip_runtime.h>

#define BB 32
#define TT 243
#define JJ 17
#define CC 256
#define BJC (BB*JJ)          // 544
#define MM (BJC*TT)          // 132192 rows (bj-major: r = bj*TT + t)
#define SIMP 244             // padded sim row stride (16B-aligned rows)
#define NEG_INF (-3.0e38f)

typedef __attribute__((ext_vector_type(8))) short bf16x8;
typedef __attribute__((ext_vector_type(4))) float f32x4;
typedef __attribute__((ext_vector_type(8))) _Float16 f16x8;
typedef __attribute__((ext_vector_type(4))) _Float16 f16x4;

__device__ __forceinline__ unsigned short f2bf(float f) {
  unsigned int u = __float_as_uint(f);
  u = (u + 0x7fffu + ((u >> 16) & 1u)) >> 16;   // RNE
  return (unsigned short)u;
}
__device__ __forceinline__ float bf2f(unsigned short s) {
  return __uint_as_float(((unsigned int)s) << 16);
}

// ---------- K0b: W_u,W_v f32 [C,C] -> wc bf16 [512,C] ----------
__global__ void k_prep_w(const float* __restrict__ Wu, const float* __restrict__ Wv,
                         unsigned short* __restrict__ wc) {
  int g = blockIdx.x * 256 + threadIdx.x;
  if (g >= 512 * (CC/4)) return;
  int c4 = g & 63;
  int n  = g >> 6;
  const float* src = (n < CC) ? (Wu + (size_t)n*CC) : (Wv + (size_t)(n-CC)*CC);
  float4 v = *reinterpret_cast<const float4*>(src + c4*4);
  ushort4 o;
  o.x = f2bf(v.x); o.y = f2bf(v.y); o.z = f2bf(v.z); o.w = f2bf(v.w);
  *reinterpret_cast<ushort4*>(wc + (size_t)n*CC + c4*4) = o;
}

// ---------- K1: u,v = x @ [Wu;Wv]^T + b ----------
// Block = 64 rows x 512 cols. A staged ONCE in 32KB LDS (bf16, XOR-swizzled
// 16B units, <=2-way). B direct global->reg (L2-resident). 2 passes (u, v),
// wave tile 32x128. 16 waves/CU residency for latency hiding.
__launch_bounds__(256, 4)
__global__ void k_uv(const float* __restrict__ x,
                     const unsigned short* __restrict__ wc,
                     const float* __restrict__ bu, const float* __restrict__ bv,
                     unsigned short* __restrict__ uo, unsigned short* __restrict__ vo) {
  __shared__ unsigned short Al[64 * 256];    // 32 KB; 16B-unit swizzle su=u^(row&31)
  const int tid  = threadIdx.x;
  const int lane = tid & 63, wid = tid >> 6;
  const int rm = (wid >> 1) * 32;            // wave row offset (0/32)
  const int cn = (wid & 1) * 128;            // wave col offset within 256 (0/128)
  const int m0 = blockIdx.x * 64;

  // ---- stage A: 64 rows x 256 k, f32 -> bf16, one pass ----
  {
    const int u = tid & 31;                  // 16B bf16-unit (8 elems) 0..31
    const int r0 = tid >> 5;                 // 8 rows per iteration
    #pragma unroll
    for (int it = 0; it < 8; ++it) {
      int row = r0 + it * 8;
      int gm = m0 + row; if (gm > MM - 1) gm = MM - 1;
      int bj = gm / TT, t = gm - bj * TT;
      int b = bj / JJ, j = bj - b * JJ;
      const float* src = x + ((size_t)(b * TT + t) * JJ + j) * CC + u * 8;
      float4 v0 = *reinterpret_cast<const float4*>(src);
      float4 v1 = *reinterpret_cast<const float4*>(src + 4);
      ushort4 lo, hi;
      lo.x = f2bf(v0.x); lo.y = f2bf(v0.y); lo.z = f2bf(v0.z); lo.w = f2bf(v0.w);
      hi.x = f2bf(v1.x); hi.y = f2bf(v1.y); hi.z = f2bf(v1.z); hi.w = f2bf(v1.w);
      int su = u ^ (row & 31);
      *reinterpret_cast<ushort4*>(&Al[row * 256 + su * 8 + 0]) = lo;
      *reinterpret_cast<ushort4*>(&Al[row * 256 + su * 8 + 4]) = hi;
    }
  }
  __syncthreads();

  const int l15 = lane & 15;
  const int kfu = lane >> 4;                 // k-unit within 32-k step (0..3)
  const int rq4 = (lane >> 4) * 4;

  #pragma unroll
  for (int pass = 0; pass < 2; ++pass) {
    const float* bsrc = pass ? bv : bu;
    unsigned short* osrc = pass ? vo : uo;
    float bias[8];
    #pragma unroll
    for (int j = 0; j < 8; ++j) bias[j] = bsrc[cn + j * 16 + l15];

    f32x4 acc[2][8];
    #pragma unroll
    for (int i = 0; i < 2; i++)
      #pragma unroll
      for (int j = 0; j < 8; j++) acc[i][j] = (f32x4){0.f, 0.f, 0.f, 0.f};

    const unsigned short* wb = wc + ((size_t)pass * 256 + cn) * CC;
    #pragma unroll
    for (int ks = 0; ks < 8; ++ks) {
      bf16x8 af[2], bfv[8];
      #pragma unroll
      for (int j = 0; j < 8; ++j)
        bfv[j] = *reinterpret_cast<const bf16x8*>(wb + (size_t)(j * 16 + l15) * CC + ks * 32 + kfu * 8);
      #pragma unroll
      for (int i = 0; i < 2; ++i) {
        int row = rm + i * 16 + l15;
        int su = (ks * 4 + kfu) ^ (row & 31);
        af[i] = *reinterpret_cast<const bf16x8*>(&Al[row * 256 + su * 8]);
      }
      #pragma unroll
      for (int i = 0; i < 2; ++i)
        #pragma unroll
        for (int j = 0; j < 8; ++j)
          acc[i][j] = __builtin_amdgcn_mfma_f32_16x16x32_bf16(af[i], bfv[j], acc[i][j], 0, 0, 0);
    }

    #pragma unroll
    for (int i = 0; i < 2; ++i) {
      #pragma unroll
      for (int q = 0; q < 4; ++q) {
        int gm = m0 + rm + i * 16 + rq4 + q;
        if (gm < MM) {
          #pragma unroll
          for (int j = 0; j < 8; ++j)
            osrc[(size_t)gm * CC + cn + j * 16 + l15] = f2bf(acc[i][j][q] + bias[j]);
        }
      }
    }
  }
}

// ---------- K2: sim = xr @ xr^T per bj via split-fp16 MFMA (3 passes) ----------
__launch_bounds__(256)
__global__ void k_sim(const float* __restrict__ x, float* __restrict__ sim) {
  __shared__ _Float16 Ah[128][40];   // +8 pad halves (16B)
  __shared__ _Float16 Al[128][40];
  __shared__ _Float16 Bh[128][40];
  __shared__ _Float16 Bl[128][40];
  const int tile = blockIdx.x;                 // 0..3: mt = tile>>1, nt = tile&1
  const int bj = blockIdx.y;
  const int m0 = (tile >> 1) * 128, n0 = (tile & 1) * 128;
  const int b = bj / JJ, jj = bj - b * JJ;
  const float* xb = x + ((size_t)b * TT * JJ + jj) * CC;   // + t*(JJ*CC) + k
  const int tid = threadIdx.x;
  const int lane = tid & 63, wid = tid >> 6;
  const int wm = (wid >> 1) * 64, wn = (wid & 1) * 64;

  const int kq = tid & 7;
  int ra[4], rb[4];
  const float *gpa[4], *gpb[4];
  #pragma unroll
  for (int it = 0; it < 4; ++it) {
    int r = (tid >> 3) + it * 32;
    ra[it] = r; rb[it] = r;
    int ta = m0 + r; if (ta > TT - 1) ta = TT - 1;
    int tb = n0 + r; if (tb > TT - 1) tb = TT - 1;
    gpa[it] = xb + (size_t)ta * (JJ * CC);
    gpb[it] = xb + (size_t)tb * (JJ * CC);
  }

  f32x4 acc[4][4];
  #pragma unroll
  for (int i = 0; i < 4; i++)
    #pragma unroll
    for (int j = 0; j < 4; j++) acc[i][j] = (f32x4){0.f, 0.f, 0.f, 0.f};

  for (int ks = 0; ks < CC; ks += 32) {
    #pragma unroll
    for (int it = 0; it < 4; ++it) {
      float4 va = *reinterpret_cast<const float4*>(gpa[it] + ks + kq * 4);
      _Float16 h0 = (_Float16)va.x, h1 = (_Float16)va.y,
               h2 = (_Float16)va.z, h3 = (_Float16)va.w;
      f16x4 hv = (f16x4){h0, h1, h2, h3};
      f16x4 lv = (f16x4){(_Float16)(va.x - (float)h0), (_Float16)(va.y - (float)h1),
                         (_Float16)(va.z - (float)h2), (_Float16)(va.w - (float)h3)};
      *reinterpret_cast<f16x4*>(&Ah[ra[it]][kq * 4]) = hv;
      *reinterpret_cast<f16x4*>(&Al[ra[it]][kq * 4]) = lv;
      float4 vb = *reinterpret_cast<const float4*>(gpb[it] + ks + kq * 4);
      h0 = (_Float16)vb.x; h1 = (_Float16)vb.y; h2 = (_Float16)vb.z; h3 = (_Float16)vb.w;
      hv = (f16x4){h0, h1, h2, h3};
      lv = (f16x4){(_Float16)(vb.x - (float)h0), (_Float16)(vb.y - (float)h1),
                   (_Float16)(vb.z - (float)h2), (_Float16)(vb.w - (float)h3)};
      *reinterpret_cast<f16x4*>(&Bh[rb[it]][kq * 4]) = hv;
      *reinterpret_cast<f16x4*>(&Bl[rb[it]][kq * 4]) = lv;
    }
    __syncthreads();
    const int kf = (lane >> 4) * 8;
    f16x8 ah[4], al[4], bh[4], bl[4];
    #pragma unroll
    for (int i = 0; i < 4; i++) {
      ah[i] = *reinterpret_cast<const f16x8*>(&Ah[wm + i * 16 + (lane & 15)][kf]);
      al[i] = *reinterpret_cast<const f16x8*>(&Al[wm + i * 16 + (lane & 15)][kf]);
    }
    #pragma unroll
    for (int j = 0; j < 4; j++) {
      bh[j] = *reinterpret_cast<const f16x8*>(&Bh[wn + j * 16 + (lane & 15)][kf]);
      bl[j] = *reinterpret_cast<const f16x8*>(&Bl[wn + j * 16 + (lane & 15)][kf]);
    }
    #pragma unroll
    for (int i = 0; i < 4; i++)
      #pragma unroll
      for (int j = 0; j < 4; j++) {
        acc[i][j] = __builtin_amdgcn_mfma_f32_16x16x32_f16(ah[i], bh[j], acc[i][j], 0, 0, 0);
        acc[i][j] = __builtin_amdgcn_mfma_f32_16x16x32_f16(ah[i], bl[j], acc[i][j], 0, 0, 0);
        acc[i][j] = __builtin_amdgcn_mfma_f32_16x16x32_f16(al[i], bh[j], acc[i][j], 0, 0, 0);
      }
    __syncthreads();
  }

  const size_t base = (size_t)bj * TT * SIMP;
  const int rq = (lane >> 4) * 4;                  // C/D: col=lane&15, row=(lane>>4)*4+q
  #pragma unroll
  for (int i = 0; i < 4; i++) {
    #pragma unroll
    for (int q = 0; q < 4; q++) {
      int n = m0 + wm + i * 16 + rq + q;
      if (n < TT) {
        #pragma unroll
        for (int j = 0; j < 4; j++) {
          int c = n0 + wn + j * 16 + (lane & 15);
          if (c < TT) sim[base + (size_t)n * SIMP + c] = acc[i][j][q];
        }
      }
    }
  }
}

// ---------- K3a: per row: thr, dis, adjacency bitmask (4 waves = 4 rows/block) ----------
__launch_bounds__(256)
__global__ void k_topk(const float* __restrict__ sim,
                       float* __restrict__ dis_o,
                       unsigned long long* __restrict__ mask_o) {
  const int l = threadIdx.x & 63, wv = threadIdx.x >> 6;
  const int r = blockIdx.x * 4 + wv;               // MM % 4 == 0
  const float* row = sim + (size_t)r * SIMP;
  float o0 = (l       < TT) ? row[l]       : NEG_INF;
  float o1 = (l + 64  < TT) ? row[l + 64]  : NEG_INF;
  float o2 = (l + 128 < TT) ? row[l + 128] : NEG_INF;
  float o3 = (l + 192 < TT) ? row[l + 192] : NEG_INF;
  float v0 = o0, v1 = o1, v2 = o2, v3 = o3;
  { float mx, mn;
    mx=fmaxf(v0,v1); mn=fminf(v0,v1); v0=mx; v1=mn;
    mx=fmaxf(v2,v3); mn=fminf(v2,v3); v2=mx; v3=mn;
    mx=fmaxf(v0,v2); mn=fminf(v0,v2); v0=mx; v2=mn;
    mx=fmaxf(v1,v3); mn=fminf(v1,v3); v1=mx; v3=mn;
    mx=fmaxf(v1,v2); mn=fminf(v1,v2); v1=mx; v2=mn; }
  int p = 0;
  float thr = NEG_INF;
  #pragma unroll
  for (int it = 0; it < 4; ++it) {
    float head = (p == 0) ? v0 : (p == 1) ? v1 : (p == 2) ? v2 : (p == 3) ? v3 : NEG_INF;
    float m = head;
    #pragma unroll
    for (int off = 1; off < 64; off <<= 1) m = fmaxf(m, __shfl_xor(m, off));
    thr = m;
    unsigned long long msk = __ballot(head == m);
    int first = __ffsll(msk) - 1;
    if (l == first) p++;
  }
  unsigned long long m0 = __ballot(o0 >= thr);
  unsigned long long m1 = __ballot(o1 >= thr);
  unsigned long long m2 = __ballot(o2 >= thr);
  unsigned long long m3 = __ballot(o3 >= thr);
  if (l == 0) {
    int deg = __popcll(m0) + __popcll(m1) + __popcll(m2) + __popcll(m3);
    dis_o[r] = rsqrtf((float)deg);
    mask_o[(size_t)r * 4 + 0] = m0;
    mask_o[(size_t)r * 4 + 1] = m1;
    mask_o[(size_t)r * 4 + 2] = m2;
    mask_o[(size_t)r * 4 + 3] = m3;
  }
}

// ---------- K3b: h = norm_adj @ v + u (one wave per row, 4 ch/lane) ----------
__launch_bounds__(512)
__global__ void k_agg(const unsigned long long* __restrict__ mask,
                      const float* __restrict__ dis, const unsigned short* __restrict__ u,
                      const unsigned short* __restrict__ v, unsigned short* __restrict__ h,
                      float* __restrict__ p1, float* __restrict__ p2) {
  __shared__ float dis_l[256];
  const int bj = blockIdx.x;
  const int tid = threadIdx.x, lane = tid & 63, wid = tid >> 6;
  if (tid < TT) dis_l[tid] = dis[(size_t)bj * TT + tid];
  __syncthreads();
  const int start = blockIdx.y * 122;
  const int cnt = blockIdx.y ? (TT - 122) : 122;
  const size_t pbase = (size_t)bj * TT;
  for (int rl = wid; rl < cnt; rl += 8) {
    const int t = start + rl;
    const size_t r = pbase + t;
    const float dr = dis_l[t];
    ushort4 uu = *reinterpret_cast<const ushort4*>(u + r * CC + lane * 4);
    float a0 = bf2f(uu.x), a1 = bf2f(uu.y), a2 = bf2f(uu.z), a3 = bf2f(uu.w);
    #pragma unroll
    for (int w4 = 0; w4 < 4; ++w4) {
      unsigned long long m = mask[r * 4 + w4];
      while (m) {
        int i = __ffsll(m) - 1;
        m &= m - 1;
        int idx = w4 * 64 + i;
        float w = dr * dis_l[idx];
        ushort4 vv = *reinterpret_cast<const ushort4*>(v + (pbase + idx) * CC + lane * 4);
        a0 = __builtin_fmaf(w, bf2f(vv.x), a0);
        a1 = __builtin_fmaf(w, bf2f(vv.y), a1);
        a2 = __builtin_fmaf(w, bf2f(vv.z), a2);
        a3 = __builtin_fmaf(w, bf2f(vv.w), a3);
      }
    }
    ushort4 hh;
    hh.x = f2bf(a0); hh.y = f2bf(a1); hh.z = f2bf(a2); hh.w = f2bf(a3);
    *reinterpret_cast<ushort4*>(h + r * CC + lane * 4) = hh;
    float s1 = a0 + a1 + a2 + a3;
    float s2 = a0*a0 + a1*a1 + a2*a2 + a3*a3;
    #pragma unroll
    for (int off = 1; off < 64; off <<= 1) { s1 += __shfl_xor(s1, off); s2 += __shfl_xor(s2, off); }
    if (lane == 0) { p1[r] = s1; p2[r] = s2; }
  }
}

// ---------- K4: BN stats per t -> scale/shift ----------
__global__ void k_bnstat(const float* __restrict__ p1, const float* __restrict__ p2,
                         const float* __restrict__ gamma, const float* __restrict__ beta,
                         float* __restrict__ scale, float* __restrict__ shift) {
  __shared__ float sA[256], sB[256];
  const int t = blockIdx.x;
  const int tid = threadIdx.x;
  float a = 0.f, b2 = 0.f;
  for (int bj = tid; bj < BJC; bj += 256) {
    a  += p1[bj * TT + t];
    b2 += p2[bj * TT + t];
  }
  sA[tid] = a; sB[tid] = b2;
  __syncthreads();
  for (int s = 128; s > 0; s >>= 1) {
    if (tid < s) { sA[tid] += sA[tid + s]; sB[tid] += sB[tid + s]; }
    __syncthreads();
  }
  if (tid == 0) {
    const float invN = 1.0f / (float)(BJC * CC);
    float mean = sA[0] * invN;
    float var  = sB[0] * invN - mean * mean;
    float sc   = rsqrtf(var + 1e-5f) * gamma[t];
    scale[t] = sc;
    shift[t] = beta[t] - mean * sc;
  }
}

// ---------- K5: out = relu(x + h*scale + shift), back to [B,T,J,C] ----------
__global__ void k_out(const float* __restrict__ x, const unsigned short* __restrict__ h,
                      const float* __restrict__ scale, const float* __restrict__ shift,
                      float* __restrict__ out) {
  int g = blockIdx.x * 256 + threadIdx.x;
  if (g >= MM * (CC/4)) return;
  int c4  = g & 63;
  int rowx = g >> 6;
  int b   = rowx / (TT*JJ);
  int rem = rowx - b*(TT*JJ);
  int t   = rem / JJ;
  int j   = rem - t*JJ;
  size_t hoff = ((size_t)(b*JJ + j) * TT + t) * CC + c4*4;
  float4 xv = *reinterpret_cast<const float4*>(x + (size_t)rowx*CC + c4*4);
  ushort4 hv = *reinterpret_cast<const ushort4*>(h + hoff);
  float sc = scale[t], sh = shift[t];
  float4 o;
  o.x = fmaxf(xv.x + bf2f(hv.x)*sc + sh, 0.f);
  o.y = fmaxf(xv.y + bf2f(hv.y)*sc + sh, 0.f);
  o.z = fmaxf(xv.z + bf2f(hv.z)*sc + sh, 0.f);
  o.w = fmaxf(xv.w + bf2f(hv.w)*sc + sh, 0.f);
  *reinterpret_cast<float4*>(out + (size_t)rowx*CC + c4*4) = o;
}

extern "C" void kernel_launch(void* const* d_in, const int* in_sizes, int n_in,
                              void* d_out, int out_size, void* d_ws, size_t ws_size,
                              hipStream_t stream) {
  const float* x     = (const float*)d_in[0];
  const float* Wu    = (const float*)d_in[1];
  const float* bu    = (const float*)d_in[2];
  const float* Wv    = (const float*)d_in[3];
  const float* bv    = (const float*)d_in[4];
  const float* gamma = (const float*)d_in[5];
  const float* beta  = (const float*)d_in[6];
  float* out = (float*)d_out;

  char* ws = (char*)d_ws;
  size_t off = 0;
  auto alloc = [&](size_t bytes) -> void* {
    void* p = ws + off;
    off = (off + bytes + 255) & ~(size_t)255;
    return p;
  };
  unsigned short* u   = (unsigned short*)alloc((size_t)MM * CC * 2);
  unsigned short* v   = (unsigned short*)alloc((size_t)MM * CC * 2);
  unsigned short* h   = (unsigned short*)alloc((size_t)MM * CC * 2);
  unsigned short* wc  = (unsigned short*)alloc((size_t)512 * CC * 2);
  float* sim = (float*)alloc((size_t)BJC * TT * SIMP * 4);
  float* dis = (float*)alloc((size_t)MM * 4);
  unsigned long long* msk = (unsigned long long*)alloc((size_t)MM * 4 * 8);
  float* p1    = (float*)alloc((size_t)MM * 4);
  float* p2    = (float*)alloc((size_t)MM * 4);
  float* scale = (float*)alloc(1024);
  float* shift = (float*)alloc(1024);

  if (ws_size < off) {
    hipMemsetAsync(d_out, 0, (size_t)out_size * 4, stream);
    return;
  }

  k_prep_w<<<dim3((512*(CC/4) + 255)/256), dim3(256), 0, stream>>>(Wu, Wv, wc);
  k_sim  <<<dim3(4, BJC), dim3(256), 0, stream>>>(x, sim);
  k_uv   <<<dim3((MM + 63)/64), dim3(256), 0, stream>>>(x, wc, bu, bv, u, v);
  k_topk <<<dim3(MM/4), dim3(256), 0, stream>>>(sim, dis, msk);
  k_agg  <<<dim3(BJC, 2), dim3(512), 0, stream>>>(msk, dis, u, v, h, p1, p2);
  k_bnstat<<<dim3(TT), dim3(256), 0, stream>>>(p1, p2, gamma, beta, scale, shift);
  k_out  <<<dim3((MM*(CC/4) + 255)/256), dim3(256), 0, stream>>>(x, h, scale, shift, out);
}

// Round 7
// 473.678 us; speedup vs baseline: 1.1441x; 1.1441x over previous
//
#include <hip/hip_runtime.h>

#define BB 32
#define TT 243
#define JJ 17
#define CC 256
#define BJC (BB*JJ)          // 544
#define MM (BJC*TT)          // 132192 rows (bj-major: r = bj*TT + t)
#define SIMP 244             // padded sim row stride (16B-aligned rows)
#define NEG_INF (-3.0e38f)

typedef __attribute__((ext_vector_type(8))) short bf16x8;
typedef __attribute__((ext_vector_type(4))) float f32x4;
typedef __attribute__((ext_vector_type(8))) _Float16 f16x8;
typedef __attribute__((ext_vector_type(4))) _Float16 f16x4;

__device__ __forceinline__ unsigned short f2bf(float f) {
  unsigned int u = __float_as_uint(f);
  u = (u + 0x7fffu + ((u >> 16) & 1u)) >> 16;   // RNE
  return (unsigned short)u;
}
__device__ __forceinline__ float bf2f(unsigned short s) {
  return __uint_as_float(((unsigned int)s) << 16);
}

// ---------- K0b: W_u,W_v f32 [C,C] -> wc bf16 [512,C] ----------
__global__ void k_prep_w(const float* __restrict__ Wu, const float* __restrict__ Wv,
                         unsigned short* __restrict__ wc) {
  int g = blockIdx.x * 256 + threadIdx.x;
  if (g >= 512 * (CC/4)) return;
  int c4 = g & 63;
  int n  = g >> 6;
  const float* src = (n < CC) ? (Wu + (size_t)n*CC) : (Wv + (size_t)(n-CC)*CC);
  float4 v = *reinterpret_cast<const float4*>(src + c4*4);
  ushort4 o;
  o.x = f2bf(v.x); o.y = f2bf(v.y); o.z = f2bf(v.z); o.w = f2bf(v.w);
  *reinterpret_cast<ushort4*>(wc + (size_t)n*CC + c4*4) = o;
}

// ---------- K2: sim = xr @ xr^T per bj via split-fp16 MFMA (3 passes) ----------
// Also emits xbf (x rounded to bf16, [BJ*T][C]) from the n0==0 tiles -- the
// staging already reads every x row, so the f32->bf16 pass rides for free.
__launch_bounds__(256)
__global__ void k_sim(const float* __restrict__ x, float* __restrict__ sim,
                      unsigned short* __restrict__ xbf) {
  __shared__ _Float16 Ah[128][40];   // +8 pad halves (16B)
  __shared__ _Float16 Al[128][40];
  __shared__ _Float16 Bh[128][40];
  __shared__ _Float16 Bl[128][40];
  const int tile = blockIdx.x;                 // 0..3: mt = tile>>1, nt = tile&1
  const int bj = blockIdx.y;
  const int m0 = (tile >> 1) * 128, n0 = (tile & 1) * 128;
  const int b = bj / JJ, jj = bj - b * JJ;
  const float* xb = x + ((size_t)b * TT * JJ + jj) * CC;   // + t*(JJ*CC) + k
  const int tid = threadIdx.x;
  const int lane = tid & 63, wid = tid >> 6;
  const int wm = (wid >> 1) * 64, wn = (wid & 1) * 64;
  const bool wrA = (n0 == 0);                  // tiles 0,2 write xbf

  const int kq = tid & 7;
  int ra[4], taa[4];
  const float *gpa[4], *gpb[4];
  #pragma unroll
  for (int it = 0; it < 4; ++it) {
    int r = (tid >> 3) + it * 32;
    ra[it] = r;
    int ta = m0 + r; if (ta > TT - 1) ta = TT - 1;
    int tb = n0 + r; if (tb > TT - 1) tb = TT - 1;
    taa[it] = ta;
    gpa[it] = xb + (size_t)ta * (JJ * CC);
    gpb[it] = xb + (size_t)tb * (JJ * CC);
  }

  f32x4 acc[4][4];
  #pragma unroll
  for (int i = 0; i < 4; i++)
    #pragma unroll
    for (int j = 0; j < 4; j++) acc[i][j] = (f32x4){0.f, 0.f, 0.f, 0.f};

  for (int ks = 0; ks < CC; ks += 32) {
    #pragma unroll
    for (int it = 0; it < 4; ++it) {
      float4 va = *reinterpret_cast<const float4*>(gpa[it] + ks + kq * 4);
      _Float16 h0 = (_Float16)va.x, h1 = (_Float16)va.y,
               h2 = (_Float16)va.z, h3 = (_Float16)va.w;
      f16x4 hv = (f16x4){h0, h1, h2, h3};
      f16x4 lv = (f16x4){(_Float16)(va.x - (float)h0), (_Float16)(va.y - (float)h1),
                         (_Float16)(va.z - (float)h2), (_Float16)(va.w - (float)h3)};
      *reinterpret_cast<f16x4*>(&Ah[ra[it]][kq * 4]) = hv;
      *reinterpret_cast<f16x4*>(&Al[ra[it]][kq * 4]) = lv;
      if (wrA) {
        ushort4 o;
        o.x = f2bf(va.x); o.y = f2bf(va.y); o.z = f2bf(va.z); o.w = f2bf(va.w);
        *reinterpret_cast<ushort4*>(xbf + ((size_t)bj * TT + taa[it]) * CC + ks + kq * 4) = o;
      }
      float4 vb = *reinterpret_cast<const float4*>(gpb[it] + ks + kq * 4);
      h0 = (_Float16)vb.x; h1 = (_Float16)vb.y; h2 = (_Float16)vb.z; h3 = (_Float16)vb.w;
      hv = (f16x4){h0, h1, h2, h3};
      lv = (f16x4){(_Float16)(vb.x - (float)h0), (_Float16)(vb.y - (float)h1),
                   (_Float16)(vb.z - (float)h2), (_Float16)(vb.w - (float)h3)};
      *reinterpret_cast<f16x4*>(&Bh[ra[it]][kq * 4]) = hv;
      *reinterpret_cast<f16x4*>(&Bl[ra[it]][kq * 4]) = lv;
    }
    __syncthreads();
    const int kf = (lane >> 4) * 8;
    f16x8 ah[4], al[4], bh[4], bl[4];
    #pragma unroll
    for (int i = 0; i < 4; i++) {
      ah[i] = *reinterpret_cast<const f16x8*>(&Ah[wm + i * 16 + (lane & 15)][kf]);
      al[i] = *reinterpret_cast<const f16x8*>(&Al[wm + i * 16 + (lane & 15)][kf]);
    }
    #pragma unroll
    for (int j = 0; j < 4; j++) {
      bh[j] = *reinterpret_cast<const f16x8*>(&Bh[wn + j * 16 + (lane & 15)][kf]);
      bl[j] = *reinterpret_cast<const f16x8*>(&Bl[wn + j * 16 + (lane & 15)][kf]);
    }
    #pragma unroll
    for (int i = 0; i < 4; i++)
      #pragma unroll
      for (int j = 0; j < 4; j++) {
        acc[i][j] = __builtin_amdgcn_mfma_f32_16x16x32_f16(ah[i], bh[j], acc[i][j], 0, 0, 0);
        acc[i][j] = __builtin_amdgcn_mfma_f32_16x16x32_f16(ah[i], bl[j], acc[i][j], 0, 0, 0);
        acc[i][j] = __builtin_amdgcn_mfma_f32_16x16x32_f16(al[i], bh[j], acc[i][j], 0, 0, 0);
      }
    __syncthreads();
  }

  const size_t base = (size_t)bj * TT * SIMP;
  const int rq = (lane >> 4) * 4;                  // C/D: col=lane&15, row=(lane>>4)*4+q
  #pragma unroll
  for (int i = 0; i < 4; i++) {
    #pragma unroll
    for (int q = 0; q < 4; q++) {
      int n = m0 + wm + i * 16 + rq + q;
      if (n < TT) {
        #pragma unroll
        for (int j = 0; j < 4; j++) {
          int c = n0 + wn + j * 16 + (lane & 15);
          if (c < TT) sim[base + (size_t)n * SIMP + c] = acc[i][j][q];
        }
      }
    }
  }
}

// ---------- K1: u,v = xbf @ [Wu;Wv]^T + b  (k_sim-style LDS-staged GEMM) ----------
// Tile 128 rows x 128 cols, BK=64, 4 waves of 32x128 (acc[2][8]).
// A and B both staged in LDS (stride 72 elems = 144B, 16B-aligned).
// Grid (4 coltiles, 1033 rowtiles), coltile fastest -> A-panel L2 reuse.
__launch_bounds__(256)
__global__ void k_uv(const unsigned short* __restrict__ xbf,
                     const unsigned short* __restrict__ wc,
                     const float* __restrict__ bu, const float* __restrict__ bv,
                     unsigned short* __restrict__ uo, unsigned short* __restrict__ vo) {
  __shared__ unsigned short Asm[128 * 72];
  __shared__ unsigned short Bsm[128 * 72];
  const int tid  = threadIdx.x;
  const int lane = tid & 63, wid = tid >> 6;
  const int ct = blockIdx.x;                 // col tile 0..3
  const int m0 = blockIdx.y * 128;
  const int rm = wid * 32;
  const int l15 = lane & 15;
  const int ku = lane >> 4;                  // 0..3

  const float* bsrc = (ct < 2) ? bu : bv;
  unsigned short* osrc = (ct < 2) ? uo : vo;
  const int cb = (ct & 1) * 128;             // col offset within u or v

  float bias[8];
  #pragma unroll
  for (int j = 0; j < 8; ++j) bias[j] = bsrc[cb + j * 16 + l15];

  f32x4 acc[2][8];
  #pragma unroll
  for (int i = 0; i < 2; i++)
    #pragma unroll
    for (int j = 0; j < 8; j++) acc[i][j] = (f32x4){0.f, 0.f, 0.f, 0.f};

  const int srow = tid >> 1, sh = tid & 1;
  int gma = m0 + srow; if (gma > MM - 1) gma = MM - 1;
  const unsigned short* ga = xbf + (size_t)gma * CC + sh * 32;
  const unsigned short* gb = wc + (size_t)(ct * 128 + srow) * CC + sh * 32;
  unsigned short* sa = &Asm[srow * 72 + sh * 32];
  unsigned short* sb = &Bsm[srow * 72 + sh * 32];

  #pragma unroll
  for (int ks = 0; ks < 4; ++ks) {
    if (ks) __syncthreads();
    #pragma unroll
    for (int s = 0; s < 4; ++s) {
      *reinterpret_cast<uint4*>(sa + s * 8) =
        *reinterpret_cast<const uint4*>(ga + ks * 64 + s * 8);
      *reinterpret_cast<uint4*>(sb + s * 8) =
        *reinterpret_cast<const uint4*>(gb + ks * 64 + s * 8);
    }
    __syncthreads();
    #pragma unroll
    for (int kh = 0; kh < 2; ++kh) {
      const int ko = kh * 32 + ku * 8;
      bf16x8 af[2], bfv[8];
      #pragma unroll
      for (int i = 0; i < 2; ++i)
        af[i] = *reinterpret_cast<const bf16x8*>(&Asm[(rm + i * 16 + l15) * 72 + ko]);
      #pragma unroll
      for (int j = 0; j < 8; ++j)
        bfv[j] = *reinterpret_cast<const bf16x8*>(&Bsm[(j * 16 + l15) * 72 + ko]);
      #pragma unroll
      for (int i = 0; i < 2; ++i)
        #pragma unroll
        for (int j = 0; j < 8; ++j)
          acc[i][j] = __builtin_amdgcn_mfma_f32_16x16x32_bf16(af[i], bfv[j], acc[i][j], 0, 0, 0);
    }
  }

  #pragma unroll
  for (int i = 0; i < 2; ++i) {
    #pragma unroll
    for (int q = 0; q < 4; ++q) {
      int gm = m0 + rm + i * 16 + ku * 4 + q;
      if (gm < MM) {
        #pragma unroll
        for (int j = 0; j < 8; ++j)
          osrc[(size_t)gm * CC + cb + j * 16 + l15] = f2bf(acc[i][j][q] + bias[j]);
      }
    }
  }
}

// ---------- K3a: per row: thr, dis, adjacency bitmask (4 waves = 4 rows/block) ----------
__launch_bounds__(256)
__global__ void k_topk(const float* __restrict__ sim,
                       float* __restrict__ dis_o,
                       unsigned long long* __restrict__ mask_o) {
  const int l = threadIdx.x & 63, wv = threadIdx.x >> 6;
  const int r = blockIdx.x * 4 + wv;               // MM % 4 == 0
  const float* row = sim + (size_t)r * SIMP;
  float o0 = (l       < TT) ? row[l]       : NEG_INF;
  float o1 = (l + 64  < TT) ? row[l + 64]  : NEG_INF;
  float o2 = (l + 128 < TT) ? row[l + 128] : NEG_INF;
  float o3 = (l + 192 < TT) ? row[l + 192] : NEG_INF;
  float v0 = o0, v1 = o1, v2 = o2, v3 = o3;
  { float mx, mn;
    mx=fmaxf(v0,v1); mn=fminf(v0,v1); v0=mx; v1=mn;
    mx=fmaxf(v2,v3); mn=fminf(v2,v3); v2=mx; v3=mn;
    mx=fmaxf(v0,v2); mn=fminf(v0,v2); v0=mx; v2=mn;
    mx=fmaxf(v1,v3); mn=fminf(v1,v3); v1=mx; v3=mn;
    mx=fmaxf(v1,v2); mn=fminf(v1,v2); v1=mx; v2=mn; }
  int p = 0;
  float thr = NEG_INF;
  #pragma unroll
  for (int it = 0; it < 4; ++it) {
    float head = (p == 0) ? v0 : (p == 1) ? v1 : (p == 2) ? v2 : (p == 3) ? v3 : NEG_INF;
    float m = head;
    #pragma unroll
    for (int off = 1; off < 64; off <<= 1) m = fmaxf(m, __shfl_xor(m, off));
    thr = m;
    unsigned long long msk = __ballot(head == m);
    int first = __ffsll(msk) - 1;
    if (l == first) p++;
  }
  unsigned long long m0 = __ballot(o0 >= thr);
  unsigned long long m1 = __ballot(o1 >= thr);
  unsigned long long m2 = __ballot(o2 >= thr);
  unsigned long long m3 = __ballot(o3 >= thr);
  if (l == 0) {
    int deg = __popcll(m0) + __popcll(m1) + __popcll(m2) + __popcll(m3);
    dis_o[r] = rsqrtf((float)deg);
    mask_o[(size_t)r * 4 + 0] = m0;
    mask_o[(size_t)r * 4 + 1] = m1;
    mask_o[(size_t)r * 4 + 2] = m2;
    mask_o[(size_t)r * 4 + 3] = m3;
  }
}

// ---------- K3b: h = norm_adj @ v + u (one wave per row, 4 ch/lane) ----------
__launch_bounds__(512)
__global__ void k_agg(const unsigned long long* __restrict__ mask,
                      const float* __restrict__ dis, const unsigned short* __restrict__ u,
                      const unsigned short* __restrict__ v, unsigned short* __restrict__ h,
                      float* __restrict__ p1, float* __restrict__ p2) {
  __shared__ float dis_l[256];
  const int bj = blockIdx.x;
  const int tid = threadIdx.x, lane = tid & 63, wid = tid >> 6;
  if (tid < TT) dis_l[tid] = dis[(size_t)bj * TT + tid];
  __syncthreads();
  const int start = blockIdx.y * 122;
  const int cnt = blockIdx.y ? (TT - 122) : 122;
  const size_t pbase = (size_t)bj * TT;
  for (int rl = wid; rl < cnt; rl += 8) {
    const int t = start + rl;
    const size_t r = pbase + t;
    const float dr = dis_l[t];
    ushort4 uu = *reinterpret_cast<const ushort4*>(u + r * CC + lane * 4);
    float a0 = bf2f(uu.x), a1 = bf2f(uu.y), a2 = bf2f(uu.z), a3 = bf2f(uu.w);
    #pragma unroll
    for (int w4 = 0; w4 < 4; ++w4) {
      unsigned long long m = mask[r * 4 + w4];
      while (m) {
        int i = __ffsll(m) - 1;
        m &= m - 1;
        int idx = w4 * 64 + i;
        float w = dr * dis_l[idx];
        ushort4 vv = *reinterpret_cast<const ushort4*>(v + (pbase + idx) * CC + lane * 4);
        a0 = __builtin_fmaf(w, bf2f(vv.x), a0);
        a1 = __builtin_fmaf(w, bf2f(vv.y), a1);
        a2 = __builtin_fmaf(w, bf2f(vv.z), a2);
        a3 = __builtin_fmaf(w, bf2f(vv.w), a3);
      }
    }
    ushort4 hh;
    hh.x = f2bf(a0); hh.y = f2bf(a1); hh.z = f2bf(a2); hh.w = f2bf(a3);
    *reinterpret_cast<ushort4*>(h + r * CC + lane * 4) = hh;
    float s1 = a0 + a1 + a2 + a3;
    float s2 = a0*a0 + a1*a1 + a2*a2 + a3*a3;
    #pragma unroll
    for (int off = 1; off < 64; off <<= 1) { s1 += __shfl_xor(s1, off); s2 += __shfl_xor(s2, off); }
    if (lane == 0) { p1[r] = s1; p2[r] = s2; }
  }
}

// ---------- K4: BN stats per t -> scale/shift ----------
__global__ void k_bnstat(const float* __restrict__ p1, const float* __restrict__ p2,
                         const float* __restrict__ gamma, const float* __restrict__ beta,
                         float* __restrict__ scale, float* __restrict__ shift) {
  __shared__ float sA[256], sB[256];
  const int t = blockIdx.x;
  const int tid = threadIdx.x;
  float a = 0.f, b2 = 0.f;
  for (int bj = tid; bj < BJC; bj += 256) {
    a  += p1[bj * TT + t];
    b2 += p2[bj * TT + t];
  }
  sA[tid] = a; sB[tid] = b2;
  __syncthreads();
  for (int s = 128; s > 0; s >>= 1) {
    if (tid < s) { sA[tid] += sA[tid + s]; sB[tid] += sB[tid + s]; }
    __syncthreads();
  }
  if (tid == 0) {
    const float invN = 1.0f / (float)(BJC * CC);
    float mean = sA[0] * invN;
    float var  = sB[0] * invN - mean * mean;
    float sc   = rsqrtf(var + 1e-5f) * gamma[t];
    scale[t] = sc;
    shift[t] = beta[t] - mean * sc;
  }
}

// ---------- K5: out = relu(x + h*scale + shift), back to [B,T,J,C] ----------
__global__ void k_out(const float* __restrict__ x, const unsigned short* __restrict__ h,
                      const float* __restrict__ scale, const float* __restrict__ shift,
                      float* __restrict__ out) {
  int g = blockIdx.x * 256 + threadIdx.x;
  if (g >= MM * (CC/4)) return;
  int c4  = g & 63;
  int rowx = g >> 6;
  int b   = rowx / (TT*JJ);
  int rem = rowx - b*(TT*JJ);
  int t   = rem / JJ;
  int j   = rem - t*JJ;
  size_t hoff = ((size_t)(b*JJ + j) * TT + t) * CC + c4*4;
  float4 xv = *reinterpret_cast<const float4*>(x + (size_t)rowx*CC + c4*4);
  ushort4 hv = *reinterpret_cast<const ushort4*>(h + hoff);
  float sc = scale[t], sh = shift[t];
  float4 o;
  o.x = fmaxf(xv.x + bf2f(hv.x)*sc + sh, 0.f);
  o.y = fmaxf(xv.y + bf2f(hv.y)*sc + sh, 0.f);
  o.z = fmaxf(xv.z + bf2f(hv.z)*sc + sh, 0.f);
  o.w = fmaxf(xv.w + bf2f(hv.w)*sc + sh, 0.f);
  *reinterpret_cast<float4*>(out + (size_t)rowx*CC + c4*4) = o;
}

extern "C" void kernel_launch(void* const* d_in, const int* in_sizes, int n_in,
                              void* d_out, int out_size, void* d_ws, size_t ws_size,
                              hipStream_t stream) {
  const float* x     = (const float*)d_in[0];
  const float* Wu    = (const float*)d_in[1];
  const float* bu    = (const float*)d_in[2];
  const float* Wv    = (const float*)d_in[3];
  const float* bv    = (const float*)d_in[4];
  const float* gamma = (const float*)d_in[5];
  const float* beta  = (const float*)d_in[6];
  float* out = (float*)d_out;

  char* ws = (char*)d_ws;
  size_t off = 0;
  auto alloc = [&](size_t bytes) -> void* {
    void* p = ws + off;
    off = (off + bytes + 255) & ~(size_t)255;
    return p;
  };
  unsigned short* xbf = (unsigned short*)alloc((size_t)MM * CC * 2);
  unsigned short* u   = (unsigned short*)alloc((size_t)MM * CC * 2);
  unsigned short* v   = (unsigned short*)alloc((size_t)MM * CC * 2);
  unsigned short* h   = (unsigned short*)alloc((size_t)MM * CC * 2);
  unsigned short* wc  = (unsigned short*)alloc((size_t)512 * CC * 2);
  float* sim = (float*)alloc((size_t)BJC * TT * SIMP * 4);
  float* dis = (float*)alloc((size_t)MM * 4);
  unsigned long long* msk = (unsigned long long*)alloc((size_t)MM * 4 * 8);
  float* p1    = (float*)alloc((size_t)MM * 4);
  float* p2    = (float*)alloc((size_t)MM * 4);
  float* scale = (float*)alloc(1024);
  float* shift = (float*)alloc(1024);

  if (ws_size < off) {
    hipMemsetAsync(d_out, 0, (size_t)out_size * 4, stream);
    return;
  }

  k_prep_w<<<dim3((512*(CC/4) + 255)/256), dim3(256), 0, stream>>>(Wu, Wv, wc);
  k_sim  <<<dim3(4, BJC), dim3(256), 0, stream>>>(x, sim, xbf);
  k_uv   <<<dim3(4, (MM + 127)/128), dim3(256), 0, stream>>>(xbf, wc, bu, bv, u, v);
  k_topk <<<dim3(MM/4), dim3(256), 0, stream>>>(sim, dis, msk);
  k_agg  <<<dim3(BJC, 2), dim3(512), 0, stream>>>(msk, dis, u, v, h, p1, p2);
  k_bnstat<<<dim3(TT), dim3(256), 0, stream>>>(p1, p2, gamma, beta, scale, shift);
  k_out  <<<dim3((MM*(CC/4) + 255)/256), dim3(256), 0, stream>>>(x, h, scale, shift, out);
}

// Round 8
// 435.109 us; speedup vs baseline: 1.2455x; 1.0886x over previous
//
#include <hip/hip_runtime.h>

#define BB 32
#define TT 243
#define JJ 17
#define CC 256
#define BJC (BB*JJ)          // 544
#define MM (BJC*TT)          // 132192 rows (bj-major: r = bj*TT + t)
#define MMPAD 132224         // 1033*128
#define SIMP 244             // padded sim row stride
#define NEG_INF (-3.0e38f)

typedef __attribute__((ext_vector_type(8))) short bf16x8;
typedef __attribute__((ext_vector_type(4))) float f32x4;
typedef __attribute__((ext_vector_type(8))) _Float16 f16x8;
typedef __attribute__((ext_vector_type(4))) _Float16 f16x4;

__device__ __forceinline__ unsigned short f2bf(float f) {
  unsigned int u = __float_as_uint(f);
  u = (u + 0x7fffu + ((u >> 16) & 1u)) >> 16;   // RNE
  return (unsigned short)u;
}
__device__ __forceinline__ float bf2f(unsigned short s) {
  return __uint_as_float(((unsigned int)s) << 16);
}

// async global->LDS, 16B per lane: lds dest = uniform base + lane*16
__device__ __forceinline__ void gld16(const void* g, void* l) {
  __builtin_amdgcn_global_load_lds(
      (__attribute__((address_space(1))) void*)(g),
      (__attribute__((address_space(3))) void*)(l), 16, 0, 0);
}

// ---------- K0a: W_u,W_v f32 [C,C] -> wcp bf16 [4 ksteps][512][64] (swizzled) ----------
__launch_bounds__(256)
__global__ void k_prep_w(const float* __restrict__ Wu, const float* __restrict__ Wv,
                         unsigned short* __restrict__ wcp) {
  const int r = blockIdx.x * 4 + (threadIdx.x >> 6);   // 0..511
  const int l = threadIdx.x & 63;
  const float* src = ((r < CC) ? (Wu + (size_t)r * CC) : (Wv + (size_t)(r - CC) * CC)) + l * 4;
  float4 v = *reinterpret_cast<const float4*>(src);
  ushort4 o;
  o.x = f2bf(v.x); o.y = f2bf(v.y); o.z = f2bf(v.z); o.w = f2bf(v.w);
  const int ks = l >> 4;                 // k-plane 0..3 (64 bf16 each)
  const int u  = (l & 15) >> 1;          // 16B unit 0..7
  const int s  = u ^ (r & 7);            // bank swizzle slot
  *reinterpret_cast<ushort4*>(wcp + ((size_t)ks * 512 + r) * 64 + s * 8 + (l & 1) * 4) = o;
}

// ---------- K0b: x -> xq (f16 hi/lo, k-blocked, swizzled) + xbfp (bf16 4-plane) ----------
// xq: [bj][ks=8][row 256(pad)][8 units*16B]: units 0-3 = hi halves, 4-7 = lo; slot u^(t&7)
// xbfp: [ks=4][MMPAD][8 units*16B] bf16; slot u^(r&7)
__launch_bounds__(256)
__global__ void k_prep_x(const float* __restrict__ x,
                         unsigned short* __restrict__ xbfp,
                         _Float16* __restrict__ xq) {
  const int r = blockIdx.x * 4 + (threadIdx.x >> 6);   // 0..MM-1
  const int l = threadIdx.x & 63;
  const int bj = r / TT, t = r - bj * TT;
  const int b = bj / JJ, j = bj - b * JJ;
  float4 v = *reinterpret_cast<const float4*>(
      x + ((size_t)(b * TT + t) * JJ + j) * CC + l * 4);

  // bf16 plane write
  ushort4 o;
  o.x = f2bf(v.x); o.y = f2bf(v.y); o.z = f2bf(v.z); o.w = f2bf(v.w);
  {
    const int ks = l >> 4;
    const int u  = (l & 15) >> 1;
    const int s  = u ^ (r & 7);
    *reinterpret_cast<ushort4*>(xbfp + ((size_t)ks * MMPAD + r) * 64 + s * 8 + (l & 1) * 4) = o;
  }
  // f16 hi/lo write
  _Float16 h0 = (_Float16)v.x, h1 = (_Float16)v.y, h2 = (_Float16)v.z, h3 = (_Float16)v.w;
  f16x4 hv = (f16x4){h0, h1, h2, h3};
  f16x4 lv = (f16x4){(_Float16)(v.x - (float)h0), (_Float16)(v.y - (float)h1),
                     (_Float16)(v.z - (float)h2), (_Float16)(v.w - (float)h3)};
  {
    const int ks = l >> 3;                  // 0..7
    const int u  = (l & 7) >> 1;            // hi unit 0..3
    const int sh = u ^ (t & 7);
    const int sl = (u + 4) ^ (t & 7);
    _Float16* dq = xq + (((size_t)bj * 8 + ks) * 256 + t) * 64;
    *reinterpret_cast<f16x4*>(dq + sh * 8 + (l & 1) * 4) = hv;
    *reinterpret_cast<f16x4*>(dq + sl * 8 + (l & 1) * 4) = lv;
  }
}

// ---------- K2: sim = xr @ xr^T per bj, split-f16 3-pass, global_load_lds staged ----------
__launch_bounds__(256)
__global__ void k_sim(const _Float16* __restrict__ xq, float* __restrict__ sim) {
  __shared__ _Float16 S[2][128][64];           // [0]=A(m) tile, [1]=B(n) tile; 16KB each
  const int tile = blockIdx.x, bj = blockIdx.y;
  const int m0 = (tile >> 1) * 128, n0 = (tile & 1) * 128;
  const int tid = threadIdx.x, lane = tid & 63, wid = tid >> 6;
  const int wm = (wid >> 1) * 64, wn = (wid & 1) * 64;
  const int l15 = lane & 15, lg = lane >> 4;
  const _Float16* base = xq + (size_t)bj * 8 * 256 * 64;

  f32x4 acc[4][4];
  #pragma unroll
  for (int i = 0; i < 4; i++)
    #pragma unroll
    for (int j = 0; j < 4; j++) acc[i][j] = (f32x4){0.f, 0.f, 0.f, 0.f};

  for (int ks = 0; ks < 8; ++ks) {
    const _Float16* kb = base + (size_t)ks * 256 * 64;
    #pragma unroll
    for (int c = 0; c < 8; ++c) {                // 32 chunks x 1KB, 8 per wave
      int ch = wid * 8 + c;
      int half = ch >> 4;                        // 0=A, 1=B
      int rows0 = (ch & 15) * 8;
      int grow = (half ? n0 : m0) + rows0;
      gld16(kb + (size_t)grow * 64 + lane * 8, &S[half][rows0][0]);
    }
    __syncthreads();
    f16x8 ah[4], al[4], bh[4], bl[4];
    #pragma unroll
    for (int i = 0; i < 4; ++i) {
      int rl = wm + i * 16 + l15, s7 = rl & 7;
      ah[i] = *reinterpret_cast<const f16x8*>(&S[0][rl][((lg    ) ^ s7) * 8]);
      al[i] = *reinterpret_cast<const f16x8*>(&S[0][rl][((lg + 4) ^ s7) * 8]);
    }
    #pragma unroll
    for (int j = 0; j < 4; ++j) {
      int rl = wn + j * 16 + l15, s7 = rl & 7;
      bh[j] = *reinterpret_cast<const f16x8*>(&S[1][rl][((lg    ) ^ s7) * 8]);
      bl[j] = *reinterpret_cast<const f16x8*>(&S[1][rl][((lg + 4) ^ s7) * 8]);
    }
    #pragma unroll
    for (int i = 0; i < 4; ++i)
      #pragma unroll
      for (int j = 0; j < 4; ++j) {
        acc[i][j] = __builtin_amdgcn_mfma_f32_16x16x32_f16(ah[i], bh[j], acc[i][j], 0, 0, 0);
        acc[i][j] = __builtin_amdgcn_mfma_f32_16x16x32_f16(ah[i], bl[j], acc[i][j], 0, 0, 0);
        acc[i][j] = __builtin_amdgcn_mfma_f32_16x16x32_f16(al[i], bh[j], acc[i][j], 0, 0, 0);
      }
    __syncthreads();
  }

  const size_t sbase = (size_t)bj * TT * SIMP;
  const int rq = lg * 4;                         // C/D: col=lane&15, row=lg*4+q
  #pragma unroll
  for (int i = 0; i < 4; i++) {
    #pragma unroll
    for (int q = 0; q < 4; q++) {
      int n = m0 + wm + i * 16 + rq + q;
      if (n < TT) {
        #pragma unroll
        for (int j = 0; j < 4; j++) {
          int c = n0 + wn + j * 16 + l15;
          if (c < TT) sim[sbase + (size_t)n * SIMP + c] = acc[i][j][q];
        }
      }
    }
  }
}

// ---------- K1: u,v = xbf @ [Wu;Wv]^T + b  (same staged structure, BK=64) ----------
__launch_bounds__(256)
__global__ void k_uv(const unsigned short* __restrict__ xbfp,
                     const unsigned short* __restrict__ wcp,
                     const float* __restrict__ bu, const float* __restrict__ bv,
                     unsigned short* __restrict__ uo, unsigned short* __restrict__ vo) {
  __shared__ unsigned short S[2][128][64];       // A rows, B(weight) rows
  const int ct = blockIdx.x;                     // 0..3
  const int m0 = blockIdx.y * 128;
  const int tid = threadIdx.x, lane = tid & 63, wid = tid >> 6;
  const int rm = wid * 32;
  const int l15 = lane & 15, lg = lane >> 4;

  const float* bsrc = (ct < 2) ? bu : bv;
  unsigned short* osrc = (ct < 2) ? uo : vo;
  const int cb = (ct & 1) * 128;

  float bias[8];
  #pragma unroll
  for (int j = 0; j < 8; ++j) bias[j] = bsrc[cb + j * 16 + l15];

  f32x4 acc[2][8];
  #pragma unroll
  for (int i = 0; i < 2; i++)
    #pragma unroll
    for (int j = 0; j < 8; j++) acc[i][j] = (f32x4){0.f, 0.f, 0.f, 0.f};

  for (int ks = 0; ks < 4; ++ks) {
    #pragma unroll
    for (int c = 0; c < 8; ++c) {
      int ch = wid * 8 + c;
      int half = ch >> 4;
      int rows0 = (ch & 15) * 8;
      const unsigned short* g = half
        ? wcp  + ((size_t)ks * 512   + ct * 128 + rows0) * 64 + lane * 8
        : xbfp + ((size_t)ks * MMPAD + m0       + rows0) * 64 + lane * 8;
      gld16(g, &S[half][rows0][0]);
    }
    __syncthreads();
    #pragma unroll
    for (int kh = 0; kh < 2; ++kh) {
      bf16x8 af[2], bfv[8];
      #pragma unroll
      for (int i = 0; i < 2; ++i) {
        int rl = rm + i * 16 + l15;
        af[i] = *reinterpret_cast<const bf16x8*>(&S[0][rl][((kh * 4 + lg) ^ (rl & 7)) * 8]);
      }
      #pragma unroll
      for (int j = 0; j < 8; ++j) {
        int rl = j * 16 + l15;
        bfv[j] = *reinterpret_cast<const bf16x8*>(&S[1][rl][((kh * 4 + lg) ^ (rl & 7)) * 8]);
      }
      #pragma unroll
      for (int i = 0; i < 2; ++i)
        #pragma unroll
        for (int j = 0; j < 8; ++j)
          acc[i][j] = __builtin_amdgcn_mfma_f32_16x16x32_bf16(af[i], bfv[j], acc[i][j], 0, 0, 0);
    }
    __syncthreads();
  }

  #pragma unroll
  for (int i = 0; i < 2; ++i) {
    #pragma unroll
    for (int q = 0; q < 4; ++q) {
      int gm = m0 + rm + i * 16 + lg * 4 + q;
      if (gm < MM) {
        #pragma unroll
        for (int j = 0; j < 8; ++j)
          osrc[(size_t)gm * CC + cb + j * 16 + l15] = f2bf(acc[i][j][q] + bias[j]);
      }
    }
  }
}

// ---------- K3a: per row: thr, dis, adjacency bitmask (4 waves = 4 rows/block) ----------
__launch_bounds__(256)
__global__ void k_topk(const float* __restrict__ sim,
                       float* __restrict__ dis_o,
                       unsigned long long* __restrict__ mask_o) {
  const int l = threadIdx.x & 63, wv = threadIdx.x >> 6;
  const int r = blockIdx.x * 4 + wv;               // MM % 4 == 0
  const float* row = sim + (size_t)r * SIMP;
  float o0 = (l       < TT) ? row[l]       : NEG_INF;
  float o1 = (l + 64  < TT) ? row[l + 64]  : NEG_INF;
  float o2 = (l + 128 < TT) ? row[l + 128] : NEG_INF;
  float o3 = (l + 192 < TT) ? row[l + 192] : NEG_INF;
  float v0 = o0, v1 = o1, v2 = o2, v3 = o3;
  { float mx, mn;
    mx=fmaxf(v0,v1); mn=fminf(v0,v1); v0=mx; v1=mn;
    mx=fmaxf(v2,v3); mn=fminf(v2,v3); v2=mx; v3=mn;
    mx=fmaxf(v0,v2); mn=fminf(v0,v2); v0=mx; v2=mn;
    mx=fmaxf(v1,v3); mn=fminf(v1,v3); v1=mx; v3=mn;
    mx=fmaxf(v1,v2); mn=fminf(v1,v2); v1=mx; v2=mn; }
  int p = 0;
  float thr = NEG_INF;
  #pragma unroll
  for (int it = 0; it < 4; ++it) {
    float head = (p == 0) ? v0 : (p == 1) ? v1 : (p == 2) ? v2 : (p == 3) ? v3 : NEG_INF;
    float m = head;
    #pragma unroll
    for (int off = 1; off < 64; off <<= 1) m = fmaxf(m, __shfl_xor(m, off));
    thr = m;
    unsigned long long msk = __ballot(head == m);
    int first = __ffsll(msk) - 1;
    if (l == first) p++;
  }
  unsigned long long m0 = __ballot(o0 >= thr);
  unsigned long long m1 = __ballot(o1 >= thr);
  unsigned long long m2 = __ballot(o2 >= thr);
  unsigned long long m3 = __ballot(o3 >= thr);
  if (l == 0) {
    int deg = __popcll(m0) + __popcll(m1) + __popcll(m2) + __popcll(m3);
    dis_o[r] = rsqrtf((float)deg);
    mask_o[(size_t)r * 4 + 0] = m0;
    mask_o[(size_t)r * 4 + 1] = m1;
    mask_o[(size_t)r * 4 + 2] = m2;
    mask_o[(size_t)r * 4 + 3] = m3;
  }
}

// ---------- K3b: h = norm_adj @ v + u (one wave per row, 4 ch/lane) ----------
__launch_bounds__(512)
__global__ void k_agg(const unsigned long long* __restrict__ mask,
                      const float* __restrict__ dis, const unsigned short* __restrict__ u,
                      const unsigned short* __restrict__ v, unsigned short* __restrict__ h,
                      float* __restrict__ p1, float* __restrict__ p2) {
  __shared__ float dis_l[256];
  const int bj = blockIdx.x;
  const int tid = threadIdx.x, lane = tid & 63, wid = tid >> 6;
  if (tid < TT) dis_l[tid] = dis[(size_t)bj * TT + tid];
  __syncthreads();
  const int start = blockIdx.y * 122;
  const int cnt = blockIdx.y ? (TT - 122) : 122;
  const size_t pbase = (size_t)bj * TT;
  for (int rl = wid; rl < cnt; rl += 8) {
    const int t = start + rl;
    const size_t r = pbase + t;
    const float dr = dis_l[t];
    ushort4 uu = *reinterpret_cast<const ushort4*>(u + r * CC + lane * 4);
    float a0 = bf2f(uu.x), a1 = bf2f(uu.y), a2 = bf2f(uu.z), a3 = bf2f(uu.w);
    #pragma unroll
    for (int w4 = 0; w4 < 4; ++w4) {
      unsigned long long m = mask[r * 4 + w4];
      while (m) {
        int i = __ffsll(m) - 1;
        m &= m - 1;
        int idx = w4 * 64 + i;
        float w = dr * dis_l[idx];
        ushort4 vv = *reinterpret_cast<const ushort4*>(v + (pbase + idx) * CC + lane * 4);
        a0 = __builtin_fmaf(w, bf2f(vv.x), a0);
        a1 = __builtin_fmaf(w, bf2f(vv.y), a1);
        a2 = __builtin_fmaf(w, bf2f(vv.z), a2);
        a3 = __builtin_fmaf(w, bf2f(vv.w), a3);
      }
    }
    ushort4 hh;
    hh.x = f2bf(a0); hh.y = f2bf(a1); hh.z = f2bf(a2); hh.w = f2bf(a3);
    *reinterpret_cast<ushort4*>(h + r * CC + lane * 4) = hh;
    float s1 = a0 + a1 + a2 + a3;
    float s2 = a0*a0 + a1*a1 + a2*a2 + a3*a3;
    #pragma unroll
    for (int off = 1; off < 64; off <<= 1) { s1 += __shfl_xor(s1, off); s2 += __shfl_xor(s2, off); }
    if (lane == 0) { p1[r] = s1; p2[r] = s2; }
  }
}

// ---------- K4: BN stats per t -> scale/shift ----------
__global__ void k_bnstat(const float* __restrict__ p1, const float* __restrict__ p2,
                         const float* __restrict__ gamma, const float* __restrict__ beta,
                         float* __restrict__ scale, float* __restrict__ shift) {
  __shared__ float sA[256], sB[256];
  const int t = blockIdx.x;
  const int tid = threadIdx.x;
  float a = 0.f, b2 = 0.f;
  for (int bj = tid; bj < BJC; bj += 256) {
    a  += p1[bj * TT + t];
    b2 += p2[bj * TT + t];
  }
  sA[tid] = a; sB[tid] = b2;
  __syncthreads();
  for (int s = 128; s > 0; s >>= 1) {
    if (tid < s) { sA[tid] += sA[tid + s]; sB[tid] += sB[tid + s]; }
    __syncthreads();
  }
  if (tid == 0) {
    const float invN = 1.0f / (float)(BJC * CC);
    float mean = sA[0] * invN;
    float var  = sB[0] * invN - mean * mean;
    float sc   = rsqrtf(var + 1e-5f) * gamma[t];
    scale[t] = sc;
    shift[t] = beta[t] - mean * sc;
  }
}

// ---------- K5: out = relu(x + h*scale + shift), back to [B,T,J,C] ----------
__global__ void k_out(const float* __restrict__ x, const unsigned short* __restrict__ h,
                      const float* __restrict__ scale, const float* __restrict__ shift,
                      float* __restrict__ out) {
  int g = blockIdx.x * 256 + threadIdx.x;
  if (g >= MM * (CC/4)) return;
  int c4  = g & 63;
  int rowx = g >> 6;
  int b   = rowx / (TT*JJ);
  int rem = rowx - b*(TT*JJ);
  int t   = rem / JJ;
  int j   = rem - t*JJ;
  size_t hoff = ((size_t)(b*JJ + j) * TT + t) * CC + c4*4;
  float4 xv = *reinterpret_cast<const float4*>(x + (size_t)rowx*CC + c4*4);
  ushort4 hv = *reinterpret_cast<const ushort4*>(h + hoff);
  float sc = scale[t], sh = shift[t];
  float4 o;
  o.x = fmaxf(xv.x + bf2f(hv.x)*sc + sh, 0.f);
  o.y = fmaxf(xv.y + bf2f(hv.y)*sc + sh, 0.f);
  o.z = fmaxf(xv.z + bf2f(hv.z)*sc + sh, 0.f);
  o.w = fmaxf(xv.w + bf2f(hv.w)*sc + sh, 0.f);
  *reinterpret_cast<float4*>(out + (size_t)rowx*CC + c4*4) = o;
}

extern "C" void kernel_launch(void* const* d_in, const int* in_sizes, int n_in,
                              void* d_out, int out_size, void* d_ws, size_t ws_size,
                              hipStream_t stream) {
  const float* x     = (const float*)d_in[0];
  const float* Wu    = (const float*)d_in[1];
  const float* bu    = (const float*)d_in[2];
  const float* Wv    = (const float*)d_in[3];
  const float* bv    = (const float*)d_in[4];
  const float* gamma = (const float*)d_in[5];
  const float* beta  = (const float*)d_in[6];
  float* out = (float*)d_out;

  char* ws = (char*)d_ws;
  size_t off = 0;
  auto alloc = [&](size_t bytes) -> void* {
    void* p = ws + off;
    off = (off + bytes + 255) & ~(size_t)255;
    return p;
  };
  unsigned short* xbfp = (unsigned short*)alloc((size_t)4 * MMPAD * 64 * 2);  // 67.7MB
  unsigned short* wcp  = (unsigned short*)alloc((size_t)4 * 512 * 64 * 2);
  _Float16* xq = (_Float16*)alloc((size_t)BJC * 8 * 256 * 64 * 2);            // 142.6MB
  float* sim = (float*)alloc((size_t)BJC * TT * SIMP * 4);                    // 129MB
  float* dis = (float*)alloc((size_t)MM * 4);
  unsigned long long* msk = (unsigned long long*)alloc((size_t)MM * 4 * 8);
  float* p1    = (float*)alloc((size_t)MM * 4);
  float* p2    = (float*)alloc((size_t)MM * 4);
  float* scale = (float*)alloc(1024);
  float* shift = (float*)alloc(1024);
  // aliases (strictly ordered on-stream, rewritten every call):
  // u,v live in xq's space (xq dead after k_sim; k_uv writes after)
  unsigned short* u = (unsigned short*)xq;
  unsigned short* v = u + (size_t)MM * CC;        // 2*67.68MB <= 142.6MB
  // h lives in xbfp's space (xbfp dead after k_uv; k_agg writes after)
  unsigned short* h = xbfp;

  if (ws_size < off) {
    hipMemsetAsync(d_out, 0, (size_t)out_size * 4, stream);
    return;
  }

  k_prep_w<<<dim3(512/4), dim3(256), 0, stream>>>(Wu, Wv, wcp);
  k_prep_x<<<dim3(MM/4), dim3(256), 0, stream>>>(x, xbfp, xq);
  k_sim  <<<dim3(4, BJC), dim3(256), 0, stream>>>(xq, sim);
  k_topk <<<dim3(MM/4), dim3(256), 0, stream>>>(sim, dis, msk);
  k_uv   <<<dim3(4, MMPAD/128), dim3(256), 0, stream>>>(xbfp, wcp, bu, bv, u, v);
  k_agg  <<<dim3(BJC, 2), dim3(512), 0, stream>>>(msk, dis, u, v, h, p1, p2);
  k_bnstat<<<dim3(TT), dim3(256), 0, stream>>>(p1, p2, gamma, beta, scale, shift);
  k_out  <<<dim3((MM*(CC/4) + 255)/256), dim3(256), 0, stream>>>(x, h, scale, shift, out);
}

// Round 10
// 384.355 us; speedup vs baseline: 1.4100x; 1.1320x over previous
//
#include <hip/hip_runtime.h>

#define BB 32
#define TT 243
#define JJ 17
#define CC 256
#define BJC (BB*JJ)          // 544
#define MM (BJC*TT)          // 132192 rows (compact: r = bj*TT + t)
#define FR (BJC*256)         // 139264 padded flat rows: flat = bj*256 + t
#define SIMP 244             // padded sim row stride
#define NEG_INF (-3.0e38f)

typedef __attribute__((ext_vector_type(8))) short bf16x8;
typedef __attribute__((ext_vector_type(4))) float f32x4;
typedef __attribute__((ext_vector_type(8))) _Float16 f16x8;
typedef __attribute__((ext_vector_type(4))) _Float16 f16x4;

__device__ __forceinline__ unsigned short f2bf(float f) {
  unsigned int u = __float_as_uint(f);
  u = (u + 0x7fffu + ((u >> 16) & 1u)) >> 16;   // RNE
  return (unsigned short)u;
}
__device__ __forceinline__ float bf2f(unsigned short s) {
  return __uint_as_float(((unsigned int)s) << 16);
}

// async global->LDS, 16B per lane: lds dest = uniform base + lane*16
__device__ __forceinline__ void gld16(const void* g, void* l) {
  __builtin_amdgcn_global_load_lds(
      (__attribute__((address_space(1))) void*)(g),
      (__attribute__((address_space(3))) void*)(l), 16, 0, 0);
}

// ---------- K0a: W_u,W_v f32 [C,C] -> wcp f16 [4 ksteps][512][64] (swizzled) ----------
__launch_bounds__(256)
__global__ void k_prep_w(const float* __restrict__ Wu, const float* __restrict__ Wv,
                         _Float16* __restrict__ wcp) {
  const int r = blockIdx.x * 4 + (threadIdx.x >> 6);   // 0..511
  const int l = threadIdx.x & 63;
  const float* src = ((r < CC) ? (Wu + (size_t)r * CC) : (Wv + (size_t)(r - CC) * CC)) + l * 4;
  float4 v = *reinterpret_cast<const float4*>(src);
  f16x4 hv = (f16x4){(_Float16)v.x, (_Float16)v.y, (_Float16)v.z, (_Float16)v.w};
  const int ks = l >> 4;                 // k-plane 0..3 (64 f16 each)
  const int u  = (l & 15) >> 1;          // 16B unit 0..7
  const int s  = u ^ (r & 7);            // bank swizzle slot (r multiple-of-8 tiles)
  *reinterpret_cast<f16x4*>(wcp + ((size_t)ks * 512 + r) * 64 + s * 8 + (l & 1) * 4) = hv;
}

// ---------- K0b: x -> xqh/xql (f16 hi + residual lo), panel-padded flat layout ----------
// layout: [ks=4][flat=bj*256+t][8 units*8 f16]; unit u at slot u^(t&7).
// Panel bases bj*256 are 8-aligned -> read-side (local&7) unswizzle is consistent
// for BOTH k_sim (per-bj tiles) and k_uv (128-aligned flat tiles).
__launch_bounds__(256)
__global__ void k_prep_x(const float* __restrict__ x,
                         _Float16* __restrict__ xqh, _Float16* __restrict__ xql) {
  const int r = blockIdx.x * 4 + (threadIdx.x >> 6);   // compact row 0..MM-1
  const int l = threadIdx.x & 63;
  const int bj = r / TT, t = r - bj * TT;
  const int b = bj / JJ, j = bj - b * JJ;
  float4 v = *reinterpret_cast<const float4*>(
      x + ((size_t)(b * TT + t) * JJ + j) * CC + l * 4);
  _Float16 h0 = (_Float16)v.x, h1 = (_Float16)v.y, h2 = (_Float16)v.z, h3 = (_Float16)v.w;
  f16x4 hv = (f16x4){h0, h1, h2, h3};
  f16x4 lv = (f16x4){(_Float16)(v.x - (float)h0), (_Float16)(v.y - (float)h1),
                     (_Float16)(v.z - (float)h2), (_Float16)(v.w - (float)h3)};
  const int fr = bj * 256 + t;            // padded flat row
  const int ks = l >> 4;
  const int u  = (l & 15) >> 1;
  const int s  = u ^ (t & 7);             // == fr&7 since bj*256 % 8 == 0
  const size_t off = ((size_t)ks * FR + fr) * 64 + s * 8 + (l & 1) * 4;
  *reinterpret_cast<f16x4*>(xqh + off) = hv;
  *reinterpret_cast<f16x4*>(xql + off) = lv;
}

// ---------- K2: sim = xr @ xr^T per bj, 256^2 symmetric single tile ----------
// One block per bj; A-tile == B-tile (stage once). Double-buffered
// global_load_lds staging (128 KB LDS). 8 waves = 2x4, wave tile 128x64.
// Split-f16 3-pass; 32-k slice order identical to the verified r8 kernel.
__launch_bounds__(512)
__global__ void k_sim(const _Float16* __restrict__ xqh, const _Float16* __restrict__ xql,
                      float* __restrict__ sim) {
  __shared__ _Float16 Sh[2][256 * 64];   // 32 KB each
  __shared__ _Float16 Sl[2][256 * 64];
  const int bj = blockIdx.x;
  const int tid = threadIdx.x, lane = tid & 63, wid = tid >> 6;
  const int wr = wid >> 2, wc = wid & 3;          // wave tile: rows wr*128, cols wc*64
  const int l15 = lane & 15, lg = lane >> 4;
  const size_t rb = (size_t)bj * 256;             // 8-aligned panel base
  const size_t lsrc = (size_t)(lane >> 3) * 64 + (lane & 7) * 8;

  f32x4 acc[8][4];
  #pragma unroll
  for (int i = 0; i < 8; i++)
    #pragma unroll
    for (int j = 0; j < 4; j++) acc[i][j] = (f32x4){0.f, 0.f, 0.f, 0.f};

  auto STAGE = [&](int ks, int d) {
    const _Float16* ph = xqh + ((size_t)ks * FR + rb) * 64;
    const _Float16* pl = xql + ((size_t)ks * FR + rb) * 64;
    #pragma unroll
    for (int c = 0; c < 4; ++c) {
      const int row0 = (wid * 4 + c) * 8;              // 8 rows (1KB) per chunk
      gld16(ph + (size_t)row0 * 64 + lsrc, &Sh[d][row0 * 64]);
      gld16(pl + (size_t)row0 * 64 + lsrc, &Sl[d][row0 * 64]);
    }
  };
  auto COMPUTE = [&](int d) {
    #pragma unroll
    for (int kh = 0; kh < 2; ++kh) {
      f16x8 bhv[4], blv[4];
      #pragma unroll
      for (int j = 0; j < 4; ++j) {
        int rc = wc * 64 + j * 16 + l15;
        int sl = ((kh * 4 + lg) ^ (rc & 7)) * 8;
        bhv[j] = *reinterpret_cast<const f16x8*>(&Sh[d][rc * 64 + sl]);
        blv[j] = *reinterpret_cast<const f16x8*>(&Sl[d][rc * 64 + sl]);
      }
      #pragma unroll
      for (int i = 0; i < 8; ++i) {
        int rl = wr * 128 + i * 16 + l15;
        int sl = ((kh * 4 + lg) ^ (rl & 7)) * 8;
        f16x8 ah = *reinterpret_cast<const f16x8*>(&Sh[d][rl * 64 + sl]);
        f16x8 al = *reinterpret_cast<const f16x8*>(&Sl[d][rl * 64 + sl]);
        #pragma unroll
        for (int j = 0; j < 4; ++j) {
          acc[i][j] = __builtin_amdgcn_mfma_f32_16x16x32_f16(ah, bhv[j], acc[i][j], 0, 0, 0);
          acc[i][j] = __builtin_amdgcn_mfma_f32_16x16x32_f16(ah, blv[j], acc[i][j], 0, 0, 0);
          acc[i][j] = __builtin_amdgcn_mfma_f32_16x16x32_f16(al, bhv[j], acc[i][j], 0, 0, 0);
        }
      }
    }
  };

  STAGE(0, 0);
  __syncthreads();
  for (int ks = 0; ks < 4; ++ks) {
    if (ks < 3) STAGE(ks + 1, (ks + 1) & 1);     // prefetch overlaps compute
    COMPUTE(ks & 1);
    __syncthreads();                              // drains vmcnt -> next buf ready
  }

  const size_t sbase = (size_t)bj * TT * SIMP;
  #pragma unroll
  for (int i = 0; i < 8; ++i) {
    #pragma unroll
    for (int q = 0; q < 4; ++q) {
      int n = wr * 128 + i * 16 + lg * 4 + q;
      if (n < TT) {
        #pragma unroll
        for (int j = 0; j < 4; ++j) {
          int c = wc * 64 + j * 16 + l15;
          if (c < TT) sim[sbase + (size_t)n * SIMP + c] = acc[i][j][q];
        }
      }
    }
  }
}

// ---------- K1: u,v = x @ [Wu;Wv]^T + b  (f16 MFMA, staged, BK=64) ----------
// Tiles the PADDED flat rows (128-aligned, 8-aligned -> swizzle consistent);
// pad rows (t>=243) are skipped at the output.
__launch_bounds__(256)
__global__ void k_uv(const _Float16* __restrict__ xqh, const _Float16* __restrict__ wcp,
                     const float* __restrict__ bu, const float* __restrict__ bv,
                     unsigned short* __restrict__ uo, unsigned short* __restrict__ vo) {
  __shared__ _Float16 S[2][128][64];             // A rows, B(weight) rows
  const int ct = blockIdx.x;                     // 0..3
  const int m0 = blockIdx.y * 128;               // padded flat row base
  const int tid = threadIdx.x, lane = tid & 63, wid = tid >> 6;
  const int rm = wid * 32;
  const int l15 = lane & 15, lg = lane >> 4;

  const float* bsrc = (ct < 2) ? bu : bv;
  unsigned short* osrc = (ct < 2) ? uo : vo;
  const int cb = (ct & 1) * 128;

  float bias[8];
  #pragma unroll
  for (int j = 0; j < 8; ++j) bias[j] = bsrc[cb + j * 16 + l15];

  f32x4 acc[2][8];
  #pragma unroll
  for (int i = 0; i < 2; i++)
    #pragma unroll
    for (int j = 0; j < 8; j++) acc[i][j] = (f32x4){0.f, 0.f, 0.f, 0.f};

  for (int ks = 0; ks < 4; ++ks) {
    #pragma unroll
    for (int c = 0; c < 8; ++c) {
      int ch = wid * 8 + c;
      int half = ch >> 4;
      int rows0 = (ch & 15) * 8;
      const _Float16* g = half
        ? wcp + ((size_t)ks * 512 + ct * 128 + rows0) * 64 + lane * 8
        : xqh + ((size_t)ks * FR  + m0       + rows0) * 64 + lane * 8;
      gld16(g, &S[half][rows0][0]);
    }
    __syncthreads();
    #pragma unroll
    for (int kh = 0; kh < 2; ++kh) {
      f16x8 af[2], bfv[8];
      #pragma unroll
      for (int i = 0; i < 2; ++i) {
        int rl = rm + i * 16 + l15;
        af[i] = *reinterpret_cast<const f16x8*>(&S[0][rl][((kh * 4 + lg) ^ (rl & 7)) * 8]);
      }
      #pragma unroll
      for (int j = 0; j < 8; ++j) {
        int rl = j * 16 + l15;
        bfv[j] = *reinterpret_cast<const f16x8*>(&S[1][rl][((kh * 4 + lg) ^ (rl & 7)) * 8]);
      }
      #pragma unroll
      for (int i = 0; i < 2; ++i)
        #pragma unroll
        for (int j = 0; j < 8; ++j)
          acc[i][j] = __builtin_amdgcn_mfma_f32_16x16x32_f16(af[i], bfv[j], acc[i][j], 0, 0, 0);
    }
    __syncthreads();
  }

  #pragma unroll
  for (int i = 0; i < 2; ++i) {
    #pragma unroll
    for (int q = 0; q < 4; ++q) {
      int gf = m0 + rm + i * 16 + lg * 4 + q;    // padded flat row
      int t = gf & 255, bj = gf >> 8;
      if (t < TT) {
        size_t gm = (size_t)bj * TT + t;         // compact row
        #pragma unroll
        for (int j = 0; j < 8; ++j)
          osrc[gm * CC + cb + j * 16 + l15] = f2bf(acc[i][j][q] + bias[j]);
      }
    }
  }
}

// ---------- K3a: thr, dis, deg, neighbor list (uint8 x8) + tie-fallback masks ----------
__launch_bounds__(256)
__global__ void k_topk(const float* __restrict__ sim,
                       float* __restrict__ dis_o,
                       unsigned long long* __restrict__ mask_o,
                       unsigned char* __restrict__ nbr_o,
                       unsigned char* __restrict__ deg_o) {
  const int l = threadIdx.x & 63, wv = threadIdx.x >> 6;
  const int r = blockIdx.x * 4 + wv;               // MM % 4 == 0
  const float* row = sim + (size_t)r * SIMP;
  float o0 = (l       < TT) ? row[l]       : NEG_INF;
  float o1 = (l + 64  < TT) ? row[l + 64]  : NEG_INF;
  float o2 = (l + 128 < TT) ? row[l + 128] : NEG_INF;
  float o3 = (l + 192 < TT) ? row[l + 192] : NEG_INF;
  float v0 = o0, v1 = o1, v2 = o2, v3 = o3;
  { float mx, mn;
    mx=fmaxf(v0,v1); mn=fminf(v0,v1); v0=mx; v1=mn;
    mx=fmaxf(v2,v3); mn=fminf(v2,v3); v2=mx; v3=mn;
    mx=fmaxf(v0,v2); mn=fminf(v0,v2); v0=mx; v2=mn;
    mx=fmaxf(v1,v3); mn=fminf(v1,v3); v1=mx; v3=mn;
    mx=fmaxf(v1,v2); mn=fminf(v1,v2); v1=mx; v2=mn; }
  int p = 0;
  float thr = NEG_INF;
  #pragma unroll
  for (int it = 0; it < 4; ++it) {
    float head = (p == 0) ? v0 : (p == 1) ? v1 : (p == 2) ? v2 : (p == 3) ? v3 : NEG_INF;
    float m = head;
    #pragma unroll
    for (int off = 1; off < 64; off <<= 1) m = fmaxf(m, __shfl_xor(m, off));
    thr = m;
    unsigned long long msk = __ballot(head == m);
    int first = __ffsll(msk) - 1;
    if (l == first) p++;
  }
  unsigned long long m0 = __ballot(o0 >= thr);
  unsigned long long m1 = __ballot(o1 >= thr);
  unsigned long long m2 = __ballot(o2 >= thr);
  unsigned long long m3 = __ballot(o3 >= thr);
  const unsigned long long below = (1ull << l) - 1ull;
  const int b0 = __popcll(m0);
  const int b1 = b0 + __popcll(m1);
  const int b2 = b1 + __popcll(m2);
  const size_t r8 = (size_t)r * 8;
  if (o0 >= thr) { int q = __popcll(m0 & below);      if (q < 8) nbr_o[r8 + q] = (unsigned char)l; }
  if (o1 >= thr) { int q = b0 + __popcll(m1 & below); if (q < 8) nbr_o[r8 + q] = (unsigned char)(64 + l); }
  if (o2 >= thr) { int q = b1 + __popcll(m2 & below); if (q < 8) nbr_o[r8 + q] = (unsigned char)(128 + l); }
  if (o3 >= thr) { int q = b2 + __popcll(m3 & below); if (q < 8) nbr_o[r8 + q] = (unsigned char)(192 + l); }
  if (l == 0) {
    int deg = b2 + __popcll(m3);
    dis_o[r] = rsqrtf((float)deg);
    deg_o[r] = (unsigned char)((deg > 255) ? 255 : deg);
    mask_o[(size_t)r * 4 + 0] = m0;
    mask_o[(size_t)r * 4 + 1] = m1;
    mask_o[(size_t)r * 4 + 2] = m2;
    mask_o[(size_t)r * 4 + 3] = m3;
  }
}

// ---------- K3b: h = norm_adj @ v + u  (list gather: independent loads) ----------
__launch_bounds__(512)
__global__ void k_agg(const unsigned char* __restrict__ nbr,
                      const unsigned char* __restrict__ degv,
                      const unsigned long long* __restrict__ mask,
                      const float* __restrict__ dis,
                      const unsigned short* __restrict__ u,
                      const unsigned short* __restrict__ v,
                      unsigned short* __restrict__ h,
                      float* __restrict__ p1, float* __restrict__ p2) {
  __shared__ float dis_l[256];
  const int bj = blockIdx.x;
  const int tid = threadIdx.x, lane = tid & 63, wid = tid >> 6;
  if (tid < TT) dis_l[tid] = dis[(size_t)bj * TT + tid];
  __syncthreads();
  const int start = blockIdx.y * 122;
  const int cnt = blockIdx.y ? (TT - 122) : 122;
  const size_t pbase = (size_t)bj * TT;
  const int co = lane * 4;
  for (int rl = wid; rl < cnt; rl += 8) {
    const int t = start + rl;
    const size_t r = pbase + t;
    const float dr = dis_l[t];
    const int dg = degv[r];
    const unsigned long long nb = *reinterpret_cast<const unsigned long long*>(nbr + r * 8);
    ushort4 uu = *reinterpret_cast<const ushort4*>(u + r * CC + co);
    float a0 = bf2f(uu.x), a1 = bf2f(uu.y), a2 = bf2f(uu.z), a3 = bf2f(uu.w);
    if (dg <= 8) {
      const int i0 = (int)(nb & 255), i1 = (int)((nb >> 8) & 255),
                i2 = (int)((nb >> 16) & 255), i3 = (int)((nb >> 24) & 255);
      ushort4 w0v = *reinterpret_cast<const ushort4*>(v + (pbase + i0) * CC + co);
      ushort4 w1v = *reinterpret_cast<const ushort4*>(v + (pbase + i1) * CC + co);
      ushort4 w2v = *reinterpret_cast<const ushort4*>(v + (pbase + i2) * CC + co);
      ushort4 w3v = *reinterpret_cast<const ushort4*>(v + (pbase + i3) * CC + co);
      const float w0 = dr * dis_l[i0], w1 = dr * dis_l[i1],
                  w2 = dr * dis_l[i2], w3 = dr * dis_l[i3];
      a0 = __builtin_fmaf(w0, bf2f(w0v.x), a0); a1 = __builtin_fmaf(w0, bf2f(w0v.y), a1);
      a2 = __builtin_fmaf(w0, bf2f(w0v.z), a2); a3 = __builtin_fmaf(w0, bf2f(w0v.w), a3);
      a0 = __builtin_fmaf(w1, bf2f(w1v.x), a0); a1 = __builtin_fmaf(w1, bf2f(w1v.y), a1);
      a2 = __builtin_fmaf(w1, bf2f(w1v.z), a2); a3 = __builtin_fmaf(w1, bf2f(w1v.w), a3);
      a0 = __builtin_fmaf(w2, bf2f(w2v.x), a0); a1 = __builtin_fmaf(w2, bf2f(w2v.y), a1);
      a2 = __builtin_fmaf(w2, bf2f(w2v.z), a2); a3 = __builtin_fmaf(w2, bf2f(w2v.w), a3);
      a0 = __builtin_fmaf(w3, bf2f(w3v.x), a0); a1 = __builtin_fmaf(w3, bf2f(w3v.y), a1);
      a2 = __builtin_fmaf(w3, bf2f(w3v.z), a2); a3 = __builtin_fmaf(w3, bf2f(w3v.w), a3);
      #pragma unroll
      for (int e = 4; e < 8; ++e) {
        if (e < dg) {
          const int ix = (int)((nb >> (8 * e)) & 255);
          const float we = dr * dis_l[ix];
          ushort4 vv = *reinterpret_cast<const ushort4*>(v + (pbase + ix) * CC + co);
          a0 = __builtin_fmaf(we, bf2f(vv.x), a0); a1 = __builtin_fmaf(we, bf2f(vv.y), a1);
          a2 = __builtin_fmaf(we, bf2f(vv.z), a2); a3 = __builtin_fmaf(we, bf2f(vv.w), a3);
        }
      }
    } else {                                     // rare tie overflow: mask decode
      #pragma unroll
      for (int w4 = 0; w4 < 4; ++w4) {
        unsigned long long m = mask[r * 4 + w4];
        while (m) {
          int i = __ffsll(m) - 1;
          m &= m - 1;
          int idx = w4 * 64 + i;
          float w = dr * dis_l[idx];
          ushort4 vv = *reinterpret_cast<const ushort4*>(v + (pbase + idx) * CC + co);
          a0 = __builtin_fmaf(w, bf2f(vv.x), a0);
          a1 = __builtin_fmaf(w, bf2f(vv.y), a1);
          a2 = __builtin_fmaf(w, bf2f(vv.z), a2);
          a3 = __builtin_fmaf(w, bf2f(vv.w), a3);
        }
      }
    }
    ushort4 hh;
    hh.x = f2bf(a0); hh.y = f2bf(a1); hh.z = f2bf(a2); hh.w = f2bf(a3);
    *reinterpret_cast<ushort4*>(h + r * CC + co) = hh;
    float s1 = a0 + a1 + a2 + a3;
    float s2 = a0*a0 + a1*a1 + a2*a2 + a3*a3;
    #pragma unroll
    for (int off = 1; off < 64; off <<= 1) { s1 += __shfl_xor(s1, off); s2 += __shfl_xor(s2, off); }
    if (lane == 0) { p1[r] = s1; p2[r] = s2; }
  }
}

// ---------- K4: BN stats per t -> scale/shift ----------
__global__ void k_bnstat(const float* __restrict__ p1, const float* __restrict__ p2,
                         const float* __restrict__ gamma, const float* __restrict__ beta,
                         float* __restrict__ scale, float* __restrict__ shift) {
  __shared__ float sA[256], sB[256];
  const int t = blockIdx.x;
  const int tid = threadIdx.x;
  float a = 0.f, b2 = 0.f;
  for (int bj = tid; bj < BJC; bj += 256) {
    a  += p1[bj * TT + t];
    b2 += p2[bj * TT + t];
  }
  sA[tid] = a; sB[tid] = b2;
  __syncthreads();
  for (int s = 128; s > 0; s >>= 1) {
    if (tid < s) { sA[tid] += sA[tid + s]; sB[tid] += sB[tid + s]; }
    __syncthreads();
  }
  if (tid == 0) {
    const float invN = 1.0f / (float)(BJC * CC);
    float mean = sA[0] * invN;
    float var  = sB[0] * invN - mean * mean;
    float sc   = rsqrtf(var + 1e-5f) * gamma[t];
    scale[t] = sc;
    shift[t] = beta[t] - mean * sc;
  }
}

// ---------- K5: out = relu(x + h*scale + shift), back to [B,T,J,C] ----------
__global__ void k_out(const float* __restrict__ x, const unsigned short* __restrict__ h,
                      const float* __restrict__ scale, const float* __restrict__ shift,
                      float* __restrict__ out) {
  int g = blockIdx.x * 256 + threadIdx.x;
  if (g >= MM * (CC/4)) return;
  int c4  = g & 63;
  int rowx = g >> 6;
  int b   = rowx / (TT*JJ);
  int rem = rowx - b*(TT*JJ);
  int t   = rem / JJ;
  int j   = rem - t*JJ;
  size_t hoff = ((size_t)(b*JJ + j) * TT + t) * CC + c4*4;
  float4 xv = *reinterpret_cast<const float4*>(x + (size_t)rowx*CC + c4*4);
  ushort4 hv = *reinterpret_cast<const ushort4*>(h + hoff);
  float sc = scale[t], sh = shift[t];
  float4 o;
  o.x = fmaxf(xv.x + bf2f(hv.x)*sc + sh, 0.f);
  o.y = fmaxf(xv.y + bf2f(hv.y)*sc + sh, 0.f);
  o.z = fmaxf(xv.z + bf2f(hv.z)*sc + sh, 0.f);
  o.w = fmaxf(xv.w + bf2f(hv.w)*sc + sh, 0.f);
  *reinterpret_cast<float4*>(out + (size_t)rowx*CC + c4*4) = o;
}

extern "C" void kernel_launch(void* const* d_in, const int* in_sizes, int n_in,
                              void* d_out, int out_size, void* d_ws, size_t ws_size,
                              hipStream_t stream) {
  const float* x     = (const float*)d_in[0];
  const float* Wu    = (const float*)d_in[1];
  const float* bu    = (const float*)d_in[2];
  const float* Wv    = (const float*)d_in[3];
  const float* bv    = (const float*)d_in[4];
  const float* gamma = (const float*)d_in[5];
  const float* beta  = (const float*)d_in[6];
  float* out = (float*)d_out;

  char* ws = (char*)d_ws;
  size_t off = 0;
  auto alloc = [&](size_t bytes) -> void* {
    void* p = ws + off;
    off = (off + bytes + 255) & ~(size_t)255;
    return p;
  };
  _Float16* xqh = (_Float16*)alloc((size_t)4 * FR * 64 * 2);      // 71.3MB
  _Float16* xql = (_Float16*)alloc((size_t)4 * FR * 64 * 2);      // 71.3MB
  _Float16* wcp = (_Float16*)alloc((size_t)4 * 512 * 64 * 2);
  float* sim = (float*)alloc((size_t)BJC * TT * SIMP * 4);        // 129MB
  float* dis = (float*)alloc((size_t)MM * 4);
  unsigned long long* msk = (unsigned long long*)alloc((size_t)MM * 4 * 8);
  unsigned char* nbr = (unsigned char*)alloc((size_t)MM * 8);
  unsigned char* deg = (unsigned char*)alloc((size_t)MM);
  float* p1    = (float*)alloc((size_t)MM * 4);
  float* p2    = (float*)alloc((size_t)MM * 4);
  float* scale = (float*)alloc(1024);
  float* shift = (float*)alloc(1024);
  unsigned short* v = (unsigned short*)alloc((size_t)MM * CC * 2); // 67.7MB
  // aliases (strictly stream-ordered, rewritten every call):
  // u lives in sim's space (sim dead after k_topk; k_uv writes after topk)
  unsigned short* u = (unsigned short*)sim;
  // h lives in xql's space (xql dead after k_sim)
  unsigned short* h = (unsigned short*)xql;

  if (ws_size < off) {
    hipMemsetAsync(d_out, 0, (size_t)out_size * 4, stream);
    return;
  }

  k_prep_w<<<dim3(512/4), dim3(256), 0, stream>>>(Wu, Wv, wcp);
  k_prep_x<<<dim3(MM/4), dim3(256), 0, stream>>>(x, xqh, xql);
  k_sim  <<<dim3(BJC), dim3(512), 0, stream>>>(xqh, xql, sim);
  k_topk <<<dim3(MM/4), dim3(256), 0, stream>>>(sim, dis, msk, nbr, deg);
  k_uv   <<<dim3(4, FR/128), dim3(256), 0, stream>>>(xqh, wcp, bu, bv, u, v);
  k_agg  <<<dim3(BJC, 2), dim3(512), 0, stream>>>(nbr, deg, msk, dis, u, v, h, p1, p2);
  k_bnstat<<<dim3(TT), dim3(256), 0, stream>>>(p1, p2, gamma, beta, scale, shift);
  k_out  <<<dim3((MM*(CC/4) + 255)/256), dim3(256), 0, stream>>>(x, h, scale, shift, out);
}